// Round 9
// baseline (772.444 us; speedup 1.0000x reference)
//
#include <hip/hip_runtime.h>
#include <stdint.h>

// SpikingLinearLayer: 20-step LIF over [512 batch, 2048 out] driven by
// binary (10% dense) input spikes x[20,512,2048] through W[2048,2048].
//
//  - I-recurrence is linear & spike-independent -> all 20 GEMMs fused,
//    LIF V-scan stitched at the end (4 segments, LDS handoff).
//  - x is {0,1}: C[t,b,o] = sum of W rows at active i -> fp64 ADDS only
//    (fp64 required: binary spike output flips on ~1e-7 noise near
//    threshold; margin ~2.5e-8).
//  - R5: WT in d_ws + global_load_lds_dwordx4 staging (no ds_write).
//  - R6 (reverted): hand depth-2 gather pipelining -> +v_mov, regressed.
//  - R7 (reverted): launch_bounds(512,8) spilled acc to scratch.
//  - R8: KT=32 + launch_bounds(512,6): 522us main; LDS pipe ~79% busy
//    (328us reads + 82us DMA writes) = the binding resource.
//  - R9: hybrid gather. Rows 0..17 via LDS (DMA-staged, ds_read_b128);
//    rows 18..31 via global_load_dwordx4 straight from L2-resident WT
//    (o-strip = 4MB/XCD). Splits 17.2 GB of gather traffic across the
//    LDS pipe (~231us) and the idle VMEM/L2 pipe (~218us) concurrently.

#define STEPS  20
#define BATCH  512
#define DIM    2048
#define B_TILE 2
#define O_TILE 256
#define NT     512
#define KT     32
#define HROWS  18             // rows 0..17 -> LDS path; 18..31 -> global
#define NSLAB  (DIM / KT)     // 64
#define ROWB   1024           // LDS row stride bytes == row size

#define GLOBAL_AS __attribute__((address_space(1)))
#define LDS_AS    __attribute__((address_space(3)))

// 64x64 tiles; float4 global both sides; pad-65 scalar LDS (2-way = free).
__global__ __launch_bounds__(256)
void transpose_kernel(const float* __restrict__ W, float* __restrict__ WT)
{
    __shared__ float tile[64][65];
    const int tid = threadIdx.x;
    const int c4 = (tid & 15) * 4;     // 4-column group
    const int rr = tid >> 4;           // 16 rows per pass
    const int k0 = blockIdx.x * 64, o0 = blockIdx.y * 64;
#pragma unroll
    for (int i = 0; i < 64; i += 16) {
        const float4 v = *reinterpret_cast<const float4*>(
            W + (size_t)(o0 + rr + i) * DIM + k0 + c4);
        tile[c4 + 0][rr + i] = v.x;    // tile[k][o]
        tile[c4 + 1][rr + i] = v.y;
        tile[c4 + 2][rr + i] = v.z;
        tile[c4 + 3][rr + i] = v.w;
    }
    __syncthreads();
#pragma unroll
    for (int i = 0; i < 64; i += 16) {
        float4 v;
        v.x = tile[rr + i][c4 + 0];
        v.y = tile[rr + i][c4 + 1];
        v.z = tile[rr + i][c4 + 2];
        v.w = tile[rr + i][c4 + 3];
        *reinterpret_cast<float4*>(
            WT + (size_t)(k0 + rr + i) * DIM + o0 + c4) = v;
    }
}

__global__ __launch_bounds__(NT, 6)
void snn_lif_kernel(const float* __restrict__ x,
                    const float* __restrict__ WT,
                    float* __restrict__ out)
{
    __shared__ __align__(16) float wlds[(HROWS * ROWB) / 4];   // 18 KB

    const int tid  = threadIdx.x;
    const int lane = tid & 63;
    const int w    = tid >> 6;          // wave 0..7
    const int bl   = w & 1;             // batch-local
    const int tq   = w >> 1;            // step quarter: t in [5tq, 5tq+5)
    const int o_blk = blockIdx.x & 7;   // o fastest: W strip pinned to XCD L2
    const int b_blk = blockIdx.x >> 3;
    const int b  = b_blk * B_TILE + bl;
    const int o0 = o_blk * O_TILE;

    double acc[5][4];                   // C[5tq+tt][b][lane*4 + u]
#pragma unroll
    for (int tt = 0; tt < 5; ++tt)
#pragma unroll
        for (int u = 0; u < 4; ++u) acc[tt][u] = 0.0;

    // lanes >=32 duplicate lanes 0..31 (32 rows/slab); ballot low 32 = mask
    const int kl = lane & 31;
    float xr[5];                        // prefetched x for current slab
#pragma unroll
    for (int m = 0; m < 5; ++m)
        xr[m] = x[((size_t)(tq * 5 + m) * BATCH + b) * DIM + kl];

    const char*   gb   = (const char*)wlds + (lane << 4);
    LDS_AS char*  ldsb = (LDS_AS char*)wlds;
    const float*  wsrc = WT + o0 + (lane << 2);   // lane's 16B within a row

    for (int kt = 0; kt < NSLAB; ++kt) {
        const int k0 = kt * KT;
        __syncthreads();   // gathers of slab kt-1 done; LDS reusable

        // ---- DMA-stage rows 0..HROWS-1 of slab kt (wave-uniform guard)
#pragma unroll
        for (int it = 0; it < 3; ++it) {
            const int r = w + it * 8;
            if (r < HROWS)
                __builtin_amdgcn_global_load_lds(
                    (const GLOBAL_AS void*)(wsrc + (size_t)(k0 + r) * DIM),
                    (LDS_AS void*)(ldsb + r * ROWB), 16, 0, 0);
        }

        // ---- wave-uniform active masks (bit L = row L = k0+L), 32-bit
        unsigned mk[5];
#pragma unroll
        for (int m = 0; m < 5; ++m)
            mk[m] = (unsigned)__ballot(xr[m] != 0.0f);

        __syncthreads();   // vmcnt(0) drain: DMA visible to all

        // ---- prefetch x for next slab (in flight behind the gather)
        if (kt + 1 < NSLAB) {
            const int k1 = k0 + KT;
#pragma unroll
            for (int m = 0; m < 5; ++m)
                xr[m] = x[((size_t)(tq * 5 + m) * BATCH + b) * DIM + k1 + kl];
        }

        // ---- sparse fp64 accumulate, split across two pipes:
        //      rows >= HROWS: global float4 gather from L2-resident WT
        //      rows <  HROWS: ds_read_b128 gather from LDS
#pragma unroll
        for (int m = 0; m < 5; ++m) {
            unsigned mhi = mk[m] >> HROWS;
            while (mhi) {
                const int r = __builtin_ctz(mhi);
                mhi &= mhi - 1;
                const float4 wv = *reinterpret_cast<const float4*>(
                    wsrc + (size_t)(k0 + HROWS + r) * DIM);
                acc[m][0] += (double)wv.x;
                acc[m][1] += (double)wv.y;
                acc[m][2] += (double)wv.z;
                acc[m][3] += (double)wv.w;
            }
            unsigned mlo = mk[m] & ((1u << HROWS) - 1);
            while (mlo) {
                const int r = __builtin_ctz(mlo);
                mlo &= mlo - 1;
                const float4 wv =
                    *reinterpret_cast<const float4*>(gb + (r << 10));
                acc[m][0] += (double)wv.x;
                acc[m][1] += (double)wv.y;
                acc[m][2] += (double)wv.z;
                acc[m][3] += (double)wv.w;
            }
        }
    }

    // ---- LIF scan (fp64, reference op order), 4 stitched segments
    const double A_M = 1.0 - 1.0 / 20.0;   // 0.95
    const double DTM = 1.0 / 20.0;         // 0.05
    const double A_S = 1.0 - 1.0 / 5.0;    // 0.8

    __syncthreads();                        // safe to reuse wlds
    double2* hand = reinterpret_cast<double2*>(wlds);  // [2][256] (V,I) = 8 KB
    const int hbase = bl * 256 + (lane << 2);
    const size_t obase = (size_t)o0 + (lane << 2);

    for (int seg = 0; seg < 4; ++seg) {
        if (tq == seg) {
            double V[4], I[4];
            if (seg == 0) {
#pragma unroll
                for (int u = 0; u < 4; ++u) { V[u] = 0.0; I[u] = 0.0; }
            } else {
#pragma unroll
                for (int u = 0; u < 4; ++u) {
                    const double2 h = hand[hbase + u];
                    V[u] = h.x; I[u] = h.y;
                }
            }
#pragma unroll
            for (int tt = 0; tt < 5; ++tt) {
                const int t = seg * 5 + tt;
                float4 s;
                float* sp = &s.x;
#pragma unroll
                for (int u = 0; u < 4; ++u) {
                    V[u] = A_M * V[u] + DTM * I[u];
                    float sv = 0.0f;
                    if (V[u] >= 1.0) { sv = 1.0f; V[u] = 0.0; }
                    sp[u] = sv;
                    I[u] = A_S * I[u] + acc[tt][u];
                }
                *reinterpret_cast<float4*>(
                    out + ((size_t)t * BATCH + b) * DIM + obase) = s;
            }
            if (seg < 3) {
#pragma unroll
                for (int u = 0; u < 4; ++u)
                    hand[hbase + u] = make_double2(V[u], I[u]);
            }
        }
        __syncthreads();
    }
}

extern "C" void kernel_launch(void* const* d_in, const int* in_sizes, int n_in,
                              void* d_out, int out_size, void* d_ws, size_t ws_size,
                              hipStream_t stream) {
    const float* x = (const float*)d_in[0];   // [20, 512, 2048] spikes
    const float* W = (const float*)d_in[1];   // [2048, 2048]
    float* out = (float*)d_out;               // [20, 512, 2048]
    float* WT  = (float*)d_ws;                // [2048, 2048] transposed W

    dim3 tb(256);
    dim3 tg(DIM / 64, DIM / 64);
    transpose_kernel<<<tg, tb, 0, stream>>>(W, WT);

    const int grid = (BATCH / B_TILE) * (DIM / O_TILE);  // 256 * 8 = 2048
    snn_lif_kernel<<<grid, NT, 0, stream>>>(x, WT, out);
}

// Round 10
// 580.737 us; speedup vs baseline: 1.3301x; 1.3301x over previous
//
#include <hip/hip_runtime.h>
#include <stdint.h>

// SpikingLinearLayer: 20-step LIF over [512 batch, 2048 out] driven by
// binary (10% dense) input spikes x[20,512,2048] through W[2048,2048].
//
//  - I-recurrence is linear & spike-independent -> all 20 GEMMs fused,
//    LIF V-scan stitched at the end (4 segments, LDS handoff).
//  - x is {0,1}: C[t,b,o] = sum of W rows at active i -> fp64 ADDS only
//    (fp64 required: binary spike output flips on ~1e-7 noise near
//    threshold; margin ~2.5e-8).
//  - R5: WT in d_ws + global_load_lds_dwordx4 staging (no ds_write).
//  - R6 (reverted): cross-iteration depth-2 carry -> +v_mov, regressed.
//  - R7 (reverted): launch_bounds(512,8) -> 64-VGPR cap -> acc spill.
//  - R8: KT=32 + launch_bounds(512,6): 522us main, LDS pipe 79% busy
//    (328us b128 reads + 82us DMA writes) -- the binding resource.
//  - R9 (reverted): global-gather hybrid lengthened the per-wave
//    dependent chain (L2 latency ~2x LDS) -> 700us. Loads must batch.
//  - R10: pair-unrolled gather: two ds_read_b128 issued back-to-back
//    per iteration, both consumed in-iteration (no register carry).
//    Halves the latency chain per row; LDS pipe 79% -> ~90%.

#define STEPS  20
#define BATCH  512
#define DIM    2048
#define B_TILE 2
#define O_TILE 256
#define NT     512
#define KT     32
#define NSLAB  (DIM / KT)     // 64
#define ROWB   1024           // LDS row stride bytes == row size

#define GLOBAL_AS __attribute__((address_space(1)))
#define LDS_AS    __attribute__((address_space(3)))

// 64x64 tiles; float4 global both sides; pad-65 scalar LDS (2-way = free).
__global__ __launch_bounds__(256)
void transpose_kernel(const float* __restrict__ W, float* __restrict__ WT)
{
    __shared__ float tile[64][65];
    const int tid = threadIdx.x;
    const int c4 = (tid & 15) * 4;     // 4-column group
    const int rr = tid >> 4;           // 16 rows per pass
    const int k0 = blockIdx.x * 64, o0 = blockIdx.y * 64;
#pragma unroll
    for (int i = 0; i < 64; i += 16) {
        const float4 v = *reinterpret_cast<const float4*>(
            W + (size_t)(o0 + rr + i) * DIM + k0 + c4);
        tile[c4 + 0][rr + i] = v.x;    // tile[k][o]
        tile[c4 + 1][rr + i] = v.y;
        tile[c4 + 2][rr + i] = v.z;
        tile[c4 + 3][rr + i] = v.w;
    }
    __syncthreads();
#pragma unroll
    for (int i = 0; i < 64; i += 16) {
        float4 v;
        v.x = tile[rr + i][c4 + 0];
        v.y = tile[rr + i][c4 + 1];
        v.z = tile[rr + i][c4 + 2];
        v.w = tile[rr + i][c4 + 3];
        *reinterpret_cast<float4*>(
            WT + (size_t)(k0 + rr + i) * DIM + o0 + c4) = v;
    }
}

__global__ __launch_bounds__(NT, 6)
void snn_lif_kernel(const float* __restrict__ x,
                    const float* __restrict__ WT,
                    float* __restrict__ out)
{
    __shared__ __align__(16) float wlds[(KT * ROWB) / 4];   // 32 KB

    const int tid  = threadIdx.x;
    const int lane = tid & 63;
    const int w    = tid >> 6;          // wave 0..7
    const int bl   = w & 1;             // batch-local
    const int tq   = w >> 1;            // step quarter: t in [5tq, 5tq+5)
    const int o_blk = blockIdx.x & 7;   // o fastest: W strip pinned to XCD L2
    const int b_blk = blockIdx.x >> 3;
    const int b  = b_blk * B_TILE + bl;
    const int o0 = o_blk * O_TILE;

    double acc[5][4];                   // C[5tq+tt][b][lane*4 + u]
#pragma unroll
    for (int tt = 0; tt < 5; ++tt)
#pragma unroll
        for (int u = 0; u < 4; ++u) acc[tt][u] = 0.0;

    // lanes >=32 duplicate lanes 0..31 (32 rows/slab); ballot low 32 = mask
    const int kl = lane & 31;
    float xr[5];                        // prefetched x for current slab
#pragma unroll
    for (int m = 0; m < 5; ++m)
        xr[m] = x[((size_t)(tq * 5 + m) * BATCH + b) * DIM + kl];

    const char*   gb   = (const char*)wlds + (lane << 4);
    LDS_AS char*  ldsb = (LDS_AS char*)wlds;
    const float*  wsrc = WT + o0 + (lane << 2);   // lane's 16B within a row

    for (int kt = 0; kt < NSLAB; ++kt) {
        const int k0 = kt * KT;
        __syncthreads();   // gathers of slab kt-1 done; LDS reusable

        // ---- DMA-stage slab kt: wave w stages rows {w + 8*it}, it<4.
#pragma unroll
        for (int it = 0; it < 4; ++it) {
            const int r = w + it * 8;
            __builtin_amdgcn_global_load_lds(
                (const GLOBAL_AS void*)(wsrc + (size_t)(k0 + r) * DIM),
                (LDS_AS void*)(ldsb + r * ROWB), 16, 0, 0);
        }

        // ---- wave-uniform active masks (bit L = row L = k0+L), 32-bit
        unsigned mk[5];
#pragma unroll
        for (int m = 0; m < 5; ++m)
            mk[m] = (unsigned)__ballot(xr[m] != 0.0f);

        __syncthreads();   // vmcnt(0) drain: DMA visible to all

        // ---- prefetch x for next slab (in flight behind the gather)
        if (kt + 1 < NSLAB) {
            const int k1 = k0 + KT;
#pragma unroll
            for (int m = 0; m < 5; ++m)
                xr[m] = x[((size_t)(tq * 5 + m) * BATCH + b) * DIM + k1 + kl];
        }

        // ---- sparse fp64 accumulate: pair-unrolled s_ff1 mask loop.
        //      Two ds_read_b128 issued back-to-back, both consumed in the
        //      same iteration (no cross-iteration carry -> no v_mov tax).
#pragma unroll
        for (int m = 0; m < 5; ++m) {
            unsigned msk = mk[m];
            while (msk & (msk - 1)) {     // >= 2 bits set
                const int r0 = __builtin_ctz(msk); msk &= msk - 1;
                const int r1 = __builtin_ctz(msk); msk &= msk - 1;
                const float4 va =
                    *reinterpret_cast<const float4*>(gb + (r0 << 10));
                const float4 vb =
                    *reinterpret_cast<const float4*>(gb + (r1 << 10));
                acc[m][0] += (double)va.x;
                acc[m][1] += (double)va.y;
                acc[m][2] += (double)va.z;
                acc[m][3] += (double)va.w;
                acc[m][0] += (double)vb.x;
                acc[m][1] += (double)vb.y;
                acc[m][2] += (double)vb.z;
                acc[m][3] += (double)vb.w;
            }
            if (msk) {                    // final odd row
                const int r = __builtin_ctz(msk);
                const float4 wv =
                    *reinterpret_cast<const float4*>(gb + (r << 10));
                acc[m][0] += (double)wv.x;
                acc[m][1] += (double)wv.y;
                acc[m][2] += (double)wv.z;
                acc[m][3] += (double)wv.w;
            }
        }
    }

    // ---- LIF scan (fp64, reference op order), 4 stitched segments
    const double A_M = 1.0 - 1.0 / 20.0;   // 0.95
    const double DTM = 1.0 / 20.0;         // 0.05
    const double A_S = 1.0 - 1.0 / 5.0;    // 0.8

    __syncthreads();                        // safe to reuse wlds
    double2* hand = reinterpret_cast<double2*>(wlds);  // [2][256] (V,I) = 8 KB
    const int hbase = bl * 256 + (lane << 2);
    const size_t obase = (size_t)o0 + (lane << 2);

    for (int seg = 0; seg < 4; ++seg) {
        if (tq == seg) {
            double V[4], I[4];
            if (seg == 0) {
#pragma unroll
                for (int u = 0; u < 4; ++u) { V[u] = 0.0; I[u] = 0.0; }
            } else {
#pragma unroll
                for (int u = 0; u < 4; ++u) {
                    const double2 h = hand[hbase + u];
                    V[u] = h.x; I[u] = h.y;
                }
            }
#pragma unroll
            for (int tt = 0; tt < 5; ++tt) {
                const int t = seg * 5 + tt;
                float4 s;
                float* sp = &s.x;
#pragma unroll
                for (int u = 0; u < 4; ++u) {
                    V[u] = A_M * V[u] + DTM * I[u];
                    float sv = 0.0f;
                    if (V[u] >= 1.0) { sv = 1.0f; V[u] = 0.0; }
                    sp[u] = sv;
                    I[u] = A_S * I[u] + acc[tt][u];
                }
                *reinterpret_cast<float4*>(
                    out + ((size_t)t * BATCH + b) * DIM + obase) = s;
            }
            if (seg < 3) {
#pragma unroll
                for (int u = 0; u < 4; ++u)
                    hand[hbase + u] = make_double2(V[u], I[u]);
            }
        }
        __syncthreads();
    }
}

extern "C" void kernel_launch(void* const* d_in, const int* in_sizes, int n_in,
                              void* d_out, int out_size, void* d_ws, size_t ws_size,
                              hipStream_t stream) {
    const float* x = (const float*)d_in[0];   // [20, 512, 2048] spikes
    const float* W = (const float*)d_in[1];   // [2048, 2048]
    float* out = (float*)d_out;               // [20, 512, 2048]
    float* WT  = (float*)d_ws;                // [2048, 2048] transposed W

    dim3 tb(256);
    dim3 tg(DIM / 64, DIM / 64);
    transpose_kernel<<<tg, tb, 0, stream>>>(W, WT);

    const int grid = (BATCH / B_TILE) * (DIM / O_TILE);  // 256 * 8 = 2048
    snn_lif_kernel<<<grid, NT, 0, stream>>>(x, WT, out);
}